// Round 23
// baseline (73.521 us; speedup 1.0000x reference)
//
#include <hip/hip_runtime.h>
#include <cfloat>
#include <cstdint>

#define NPTS 65536
#define DIM 256
#define NC 16
#define KSEL 2048
#define VMAX 4608
#define EPSV 1e-6f

typedef __attribute__((ext_vector_type(8))) short short8v;
typedef __attribute__((ext_vector_type(4))) float f32x4;

// ws layout (bytes):
//      0 : int bhist[512*16]   (32768)  raw per-half-chunk hist (accum -> redcent)
//  32768 : int counts[16]      (64)     (redcent scan -> select)
//  32832 : int offsets[16]     (64)
//  32896 : float csq[16]       (64)
//  32960 : float pos_stat[16]  (64)
//  33024 : float neg_stat[256] (1024)
//  34048 : ushort cfb[4096]    (8192)   centers in bf16 MFMA A-fragment order
//  65536 : int bhist2[512*16]  (32768)  scanned bases (redcent -> dist)
// 131072 : float Dmat[16*65536] (4 MB) -- also partials[512][4096] (8 MB) pre-dist
// 16842752 : int slots[65536]  (256 KB) packed (lab<<16 | rank-within-half-chunk)

#define ACC_CASE(C) case C: acc[C][0] += xv[u].x; acc[C][1] += xv[u].y; \
                            acc[C][2] += xv[u].z; acc[C][3] += xv[u].w; break;

// 512 blocks x 128 rows (one half-chunk). Waves 0/1 also ballot-rank the 128
// labels -> slots + bhist (histrank merged in). Two-phase 32KB LDS combine.
// No min-waves bound (R17: (256,4) clamped VGPR->64 and spilled acc).
__global__ void __launch_bounds__(256) k_accum(const float* __restrict__ x,
                                               const int* __restrict__ y,
                                               float* __restrict__ partials,
                                               int* __restrict__ bhist,
                                               int* __restrict__ slots) {
  __shared__ int labs[128];
  __shared__ int wcnt2[2][NC];
  __shared__ float red[2 * NC * DIM];  // 32 KB
  int t = threadIdx.x;
  int n0 = blockIdx.x * 128;
  if (t < 128) labs[t] = y[(n0 + t) * 3 + 2];
  __syncthreads();

  // merged histrank: waves 0,1 rank their 64 labels
  if (t < 128) {
    int lab = labs[t];
    int lane = t & 63, w2 = t >> 6;
    unsigned long long mymask = 0;
#pragma unroll
    for (int c = 0; c < NC; ++c) {
      unsigned long long mk = __ballot(lab == c);
      if (lane == 0) wcnt2[w2][c] = __popcll(mk);
      if (lab == c) mymask = mk;
    }
    int rank = __popcll(mymask & ((1ull << lane) - 1ull));
    // wcnt2[0] written by wave 0; wave 1 needs it -> sync below, then finish
    slots[n0 + t] = (lab << 16) | rank;  // partial (w2==1 fixed after sync)
  }
  __syncthreads();
  if (t >= 64 && t < 128) {
    int lab = labs[t];
    slots[n0 + t] += wcnt2[0][lab];
  }
  if (t < NC) bhist[blockIdx.x * NC + t] = wcnt2[0][t] + wcnt2[1][t];

  int w = t >> 6, m = t & 63;
  float acc[NC][4];
#pragma unroll
  for (int c = 0; c < NC; ++c)
#pragma unroll
    for (int j = 0; j < 4; ++j) acc[c][j] = 0.f;

  for (int r0 = 0; r0 < 32; r0 += 4) {
    float4 xv[4];
#pragma unroll
    for (int u = 0; u < 4; ++u)
      xv[u] = *(const float4*)(x + (size_t)(n0 + 32 * w + r0 + u) * DIM + 4 * m);
#pragma unroll
    for (int u = 0; u < 4; ++u) {
      int lab = __builtin_amdgcn_readfirstlane(labs[32 * w + r0 + u]);
      switch (lab) {
        ACC_CASE(0) ACC_CASE(1) ACC_CASE(2) ACC_CASE(3)
        ACC_CASE(4) ACC_CASE(5) ACC_CASE(6) ACC_CASE(7)
        ACC_CASE(8) ACC_CASE(9) ACC_CASE(10) ACC_CASE(11)
        ACC_CASE(12) ACC_CASE(13) ACC_CASE(14) ACC_CASE(15)
      }
    }
  }

  int half = w & 1;
  if (w < 2) {
#pragma unroll
    for (int c = 0; c < NC; ++c)
#pragma unroll
      for (int j = 0; j < 4; ++j)
        red[half * (NC * DIM) + c * DIM + 4 * m + j] = acc[c][j];
  }
  __syncthreads();
  if (w >= 2) {
#pragma unroll
    for (int c = 0; c < NC; ++c)
#pragma unroll
      for (int j = 0; j < 4; ++j)
        red[half * (NC * DIM) + c * DIM + 4 * m + j] += acc[c][j];
  }
  __syncthreads();
  for (int u = t; u < NC * DIM; u += 256)
    partials[(size_t)blockIdx.x * (NC * DIM) + u] = red[u] + red[NC * DIM + u];
}

// 17 blocks x 1024 thr. Blocks 0-15: class c = blockIdx -> 4-slice parallel
// reduce of 512 partials + count (512-wide wave reduce over raw bhist) +
// cfb/csq. Block 16: scan bhist -> bhist2 (separate buffer: no race with
// blocks 0-15 reading raw bhist), counts, offsets.
__global__ void __launch_bounds__(1024) k_redcent(const float* __restrict__ partials,
                                                  const int* __restrict__ bhist,
                                                  int* __restrict__ bhist2,
                                                  int* __restrict__ counts,
                                                  int* __restrict__ offsets,
                                                  float* __restrict__ csq,
                                                  unsigned short* __restrict__ cfb) {
  __shared__ int lh[512 * NC];        // 32 KB (scan block)
  __shared__ float sl[4 * 256];       // 4 KB (center blocks)
  __shared__ int segbase[16][NC];
  __shared__ int totl[NC], offl[NC];
  __shared__ int wredi[16];
  __shared__ int cnt_sh;
  __shared__ float wsum[4];
  int t = threadIdx.x;

  if (blockIdx.x < 16) {
    int c = blockIdx.x;
    int d = t & 255, s = t >> 8;  // slice 0..3
    float a = 0.f;
#pragma unroll 8
    for (int b = s * 128; b < s * 128 + 128; ++b)
      a += partials[(size_t)b * (NC * DIM) + c * DIM + d];
    sl[s * 256 + d] = a;

    // count = sum of bhist[hc][c] over 512 half-chunks
    int lane = t & 63, wv = t >> 6;
    int v = (t < 512) ? bhist[t * NC + c] : 0;
#pragma unroll
    for (int m = 1; m < 64; m <<= 1) v += __shfl_xor(v, m);
    if (lane == 0) wredi[wv] = v;
    __syncthreads();
    if (t == 0) {
      int cn = 0;
#pragma unroll
      for (int w2 = 0; w2 < 16; ++w2) cn += wredi[w2];
      cnt_sh = cn;
    }
    __syncthreads();
    if (s == 0) {
      float v4 = sl[d] + sl[256 + d] + sl[512 + d] + sl[768 + d];
      float vc = v4 / (float)cnt_sh + EPSV;
      unsigned int bits = __float_as_uint(vc);
      unsigned short h = (unsigned short)((bits + 0x7FFFu + ((bits >> 16) & 1u)) >> 16);
      int kc = d >> 5, lg = (d >> 3) & 3, j = d & 7;
      int l = lg * 16 + c;
      cfb[kc * 512 + l * 8 + j] = h;
      float q = vc * vc;
#pragma unroll
      for (int m = 1; m < 64; m <<= 1) q += __shfl_xor(q, m);
      if ((d & 63) == 0) wsum[d >> 6] = q;
    }
    __syncthreads();
    if (t == 0) csq[c] = wsum[0] + wsum[1] + wsum[2] + wsum[3];
  } else {
    // scan block: 512 half-chunks, 16 segments x 32
    for (int u = t; u < 512 * NC; u += 1024) lh[u] = bhist[u];
    __syncthreads();
    if (t < 256) {
      int c = t & 15, g = t >> 4;
      int part = 0;
#pragma unroll
      for (int b = 0; b < 32; ++b) part += lh[(g * 32 + b) * NC + c];
      segbase[g][c] = part;
    }
    __syncthreads();
    if (t < NC) {
      int tot = 0;
#pragma unroll
      for (int g2 = 0; g2 < 16; ++g2) tot += segbase[g2][t];
      totl[t] = tot;
      counts[t] = tot;
    }
    __syncthreads();
    if (t == 0) {
      int run = 0;
      for (int c2 = 0; c2 < NC; ++c2) { offl[c2] = run; offsets[c2] = run; run += totl[c2]; }
    }
    __syncthreads();
    if (t < NC) {
      int run = offl[t];
#pragma unroll
      for (int g2 = 0; g2 < 16; ++g2) { int tmp = segbase[g2][t]; segbase[g2][t] = run; run += tmp; }
    }
    __syncthreads();
    if (t < 256) {
      int c = t & 15, g = t >> 4;
      int run = segbase[g][c];
#pragma unroll
      for (int b = 0; b < 32; ++b) {
        int idx = (g * 32 + b) * NC + c;
        int tmp = lh[idx]; lh[idx] = run; run += tmp;
      }
    }
    __syncthreads();
    for (int u = t; u < 512 * NC; u += 1024) bhist2[u] = lh[u];
  }
}

__device__ __forceinline__ unsigned int cvt_pk_bf16(float lo, float hi) {
  unsigned int r;
  asm("v_cvt_pk_bf16_f32 %0, %1, %2" : "=v"(r) : "v"(lo), "v"(hi));
  return r;
}

// MFMA k_dist: D = centers(bf16) . x(bf16), xsq fp32. Slot = bhist2 base of
// this half-chunk (blockIdx>>1) + packed rank.
__global__ void __launch_bounds__(256) k_dist(const float* __restrict__ x,
                                              const unsigned short* __restrict__ cfb,
                                              const float* __restrict__ csq,
                                              const int* __restrict__ slots,
                                              const int* __restrict__ bbase,
                                              float* __restrict__ Dmat) {
  __shared__ float csql[NC];
  __shared__ int baseL[NC];
  __shared__ int slotL[64];
  int t = threadIdx.x;
  if (t < NC) {
    csql[t] = csq[t];
    baseL[t] = bbase[(blockIdx.x >> 1) * NC + t];
  }
  __syncthreads();
  int pbase = blockIdx.x * 64;
  if (t < 64) {
    int sp = slots[pbase + t];
    slotL[t] = baseL[sp >> 16] + (sp & 0xFFFF);
  }
  __syncthreads();

  int wave = t >> 6, l = t & 63;
  int lg = l >> 4;
  int pl = wave * 16 + (l & 15);
  int p = pbase + pl;

  const float4* xrow = (const float4*)(x + (size_t)p * DIM);
  float4 xa[8][2];
#pragma unroll
  for (int kc = 0; kc < 8; ++kc) {
    xa[kc][0] = xrow[kc * 8 + lg * 2 + 0];
    xa[kc][1] = xrow[kc * 8 + lg * 2 + 1];
  }

  float xsq = 0.f;
#pragma unroll
  for (int kc = 0; kc < 8; ++kc) {
    float4 a0 = xa[kc][0], a1 = xa[kc][1];
    xsq += a0.x * a0.x + a0.y * a0.y + a0.z * a0.z + a0.w * a0.w +
           a1.x * a1.x + a1.y * a1.y + a1.z * a1.z + a1.w * a1.w;
  }
  xsq += __shfl_xor(xsq, 16);
  xsq += __shfl_xor(xsq, 32);

  const uint4* cfp = (const uint4*)cfb;
  f32x4 acc = {0.f, 0.f, 0.f, 0.f};
#pragma unroll
  for (int kc = 0; kc < 8; ++kc) {
    union { unsigned int u[4]; short8v s; } xb, cf;
    float4 a0 = xa[kc][0], a1 = xa[kc][1];
    xb.u[0] = cvt_pk_bf16(a0.x, a0.y);
    xb.u[1] = cvt_pk_bf16(a0.z, a0.w);
    xb.u[2] = cvt_pk_bf16(a1.x, a1.y);
    xb.u[3] = cvt_pk_bf16(a1.z, a1.w);
    uint4 cw = cfp[kc * 64 + l];
    cf.u[0] = cw.x; cf.u[1] = cw.y; cf.u[2] = cw.z; cf.u[3] = cw.w;
    acc = __builtin_amdgcn_mfma_f32_16x16x32_bf16(cf.s, xb.s, acc, 0, 0, 0);
  }

  int slot = slotL[pl];
#pragma unroll
  for (int j = 0; j < 4; ++j) {
    int m = lg * 4 + j;
    float d2 = csql[m] - 2.f * acc[j] + xsq;
    Dmat[(size_t)m * NPTS + slot] = sqrtf(fmaxf(d2, 0.f));
  }
}

// Radix-select; bin location via wave-0 hierarchical find (no block scans).
__global__ void __launch_bounds__(512) k_select(const float* __restrict__ Dmat,
                                                const int* __restrict__ gcounts,
                                                const int* __restrict__ offsets,
                                                float* __restrict__ pos_stat,
                                                float* __restrict__ neg_stat) {
  __shared__ unsigned int keys[VMAX];
  __shared__ int hist[2048];
  __shared__ int bsel[2];
  __shared__ float wsumf[8];
  __shared__ int wsumi[8];
  int tid = threadIdx.x;
  int lane = tid & 63, wv = tid >> 6;
  int b = blockIdx.x;
  int ci = b >> 4, cl = b & 15;
  bool largest = (ci == cl);
  int cnt = gcounts[cl];
  if (cnt > VMAX) cnt = VMAX;
  int off = offsets[cl];
  const float* src = Dmat + (size_t)ci * NPTS + off;
  unsigned int inv = largest ? 0xFFFFFFFFu : 0u;
  for (int t = tid; t < cnt; t += 512) keys[t] = __float_as_uint(src[t]) ^ inv;
  __syncthreads();

  int target = KSEL;
  unsigned int pfx = 0;

  for (int u = tid; u < 2048; u += 512) hist[u] = 0;
  __syncthreads();
  for (int t = tid; t < cnt; t += 512) atomicAdd(&hist[keys[t] >> 21], 1);
  __syncthreads();
  if (tid < 64) {
    int own = 0;
#pragma unroll
    for (int j = 0; j < 32; ++j) own += hist[lane * 32 + j];
    int incl = own;
    for (int o = 1; o < 64; o <<= 1) { int n = __shfl_up(incl, o); if (lane >= o) incl += n; }
    int excl = incl - own;
    unsigned long long mk = __ballot(excl < target && target <= incl);
    int sel = __ffsll((unsigned long long)mk) - 1;
    if (lane == sel) {
      int run = excl;
      for (int j = 0; j < 32; ++j) {
        int h = hist[lane * 32 + j];
        if (run < target && target <= run + h) { bsel[0] = lane * 32 + j; bsel[1] = target - run; }
        run += h;
      }
    }
  }
  __syncthreads();
  pfx = ((unsigned int)bsel[0]) << 21; target = bsel[1];
  __syncthreads();

  for (int u = tid; u < 2048; u += 512) hist[u] = 0;
  __syncthreads();
  for (int t = tid; t < cnt; t += 512) {
    unsigned int k = keys[t];
    if ((k >> 21) == (pfx >> 21)) atomicAdd(&hist[(k >> 10) & 0x7FF], 1);
  }
  __syncthreads();
  if (tid < 64) {
    int own = 0;
#pragma unroll
    for (int j = 0; j < 32; ++j) own += hist[lane * 32 + j];
    int incl = own;
    for (int o = 1; o < 64; o <<= 1) { int n = __shfl_up(incl, o); if (lane >= o) incl += n; }
    int excl = incl - own;
    unsigned long long mk = __ballot(excl < target && target <= incl);
    int sel = __ffsll((unsigned long long)mk) - 1;
    if (lane == sel) {
      int run = excl;
      for (int j = 0; j < 32; ++j) {
        int h = hist[lane * 32 + j];
        if (run < target && target <= run + h) { bsel[0] = lane * 32 + j; bsel[1] = target - run; }
        run += h;
      }
    }
  }
  __syncthreads();
  pfx |= ((unsigned int)bsel[0]) << 10; target = bsel[1];
  __syncthreads();

  for (int u = tid; u < 1024; u += 512) hist[u] = 0;
  __syncthreads();
  for (int t = tid; t < cnt; t += 512) {
    unsigned int k = keys[t];
    if ((k >> 10) == (pfx >> 10)) atomicAdd(&hist[k & 0x3FF], 1);
  }
  __syncthreads();
  if (tid < 64) {
    int own = 0;
#pragma unroll
    for (int j = 0; j < 16; ++j) own += hist[lane * 16 + j];
    int incl = own;
    for (int o = 1; o < 64; o <<= 1) { int n = __shfl_up(incl, o); if (lane >= o) incl += n; }
    int excl = incl - own;
    unsigned long long mk = __ballot(excl < target && target <= incl);
    int sel = __ffsll((unsigned long long)mk) - 1;
    if (lane == sel) {
      int run = excl;
      for (int j = 0; j < 16; ++j) {
        int h = hist[lane * 16 + j];
        if (run < target && target <= run + h) { bsel[0] = lane * 16 + j; }
        run += h;
      }
    }
  }
  __syncthreads();
  unsigned int T = pfx | (unsigned int)bsel[0];
  float fT = __uint_as_float(T ^ inv);

  int nl = 0; float sl = 0.f;
  for (int t = tid; t < cnt; t += 512) {
    unsigned int k = keys[t];
    if (k < T) { nl++; sl += __uint_as_float(k ^ inv); }
  }
#pragma unroll
  for (int m = 1; m < 64; m <<= 1) { nl += __shfl_xor(nl, m); sl += __shfl_xor(sl, m); }
  if (lane == 0) { wsumi[wv] = nl; wsumf[wv] = sl; }
  __syncthreads();
  int n_less = 0; float s_less = 0.f;
#pragma unroll
  for (int w2 = 0; w2 < 8; ++w2) { n_less += wsumi[w2]; s_less += wsumf[w2]; }
  float mean = (s_less + (float)(KSEL - n_less) * fT) / (float)KSEL;
  __syncthreads();

  float sv = 0.f;
  for (int t = tid; t < cnt; t += 512) {
    unsigned int k = keys[t];
    if (k < T) { float d = __uint_as_float(k ^ inv) - mean; sv += d * d; }
  }
#pragma unroll
  for (int m = 1; m < 64; m <<= 1) sv += __shfl_xor(sv, m);
  if (lane == 0) wsumf[wv] = sv;
  __syncthreads();
  if (tid == 0) {
    float vs = 0.f;
#pragma unroll
    for (int w2 = 0; w2 < 8; ++w2) vs += wsumf[w2];
    float dT = fT - mean;
    float var = (vs + (float)(KSEL - n_less) * dT * dT) / (float)(KSEL - 1);
    if (largest) pos_stat[ci] = mean + 1.96f * sqrtf(var);
    else neg_stat[ci * 16 + cl] = mean - 1.96f * sqrtf(var);
  }
}

__global__ void __launch_bounds__(256) k_loss(const float* __restrict__ pos_stat,
                                              const float* __restrict__ neg_stat,
                                              float* __restrict__ out) {
  __shared__ float red[256];
  int t = threadIdx.x;
  int i = t >> 4, c = t & 15;
  float v = 0.f;
  if (i != c) v = fmaxf(1.0f + pos_stat[i] - neg_stat[t], 0.f);
  red[t] = v; __syncthreads();
  for (int st = 128; st > 0; st >>= 1) { if (t < st) red[t] += red[t + st]; __syncthreads(); }
  if (t == 0) out[0] = red[0];
}

extern "C" void kernel_launch(void* const* d_in, const int* in_sizes, int n_in,
                              void* d_out, int out_size, void* d_ws, size_t ws_size,
                              hipStream_t stream) {
  const float* x = (const float*)d_in[0];
  const int* y = (const int*)d_in[1];
  float* out = (float*)d_out;
  char* ws = (char*)d_ws;

  int* bhist = (int*)(ws + 0);
  int* counts = (int*)(ws + 32768);
  int* offsets = (int*)(ws + 32832);
  float* csq = (float*)(ws + 32896);
  float* pos_stat = (float*)(ws + 32960);
  float* neg_stat = (float*)(ws + 33024);
  unsigned short* cfb = (unsigned short*)(ws + 34048);
  int* bhist2 = (int*)(ws + 65536);
  float* Dmat = (float*)(ws + 131072);
  float* partials = (float*)(ws + 131072);  // [512][4096] = 8 MB, consumed pre-dist
  int* slots = (int*)(ws + 16842752);

  k_accum<<<512, 256, 0, stream>>>(x, y, partials, bhist, slots);
  k_redcent<<<17, 1024, 0, stream>>>(partials, bhist, bhist2, counts, offsets, csq, cfb);
  k_dist<<<1024, 256, 0, stream>>>(x, cfb, csq, slots, bhist2, Dmat);
  k_select<<<256, 512, 0, stream>>>(Dmat, counts, offsets, pos_stat, neg_stat);
  k_loss<<<1, 256, 0, stream>>>(pos_stat, neg_stat, out);
}

// Round 24
// 73.457 us; speedup vs baseline: 1.0009x; 1.0009x over previous
//
#include <hip/hip_runtime.h>
#include <cfloat>
#include <cstdint>

#define NPTS 65536
#define DIM 256
#define NC 16
#define KSEL 2048
#define VMAX 4608
#define EPSV 1e-6f

typedef __attribute__((ext_vector_type(8))) short short8v;
typedef __attribute__((ext_vector_type(4))) float f32x4;

// ws layout (bytes):
//      0 : int bhist[512*16]   (32768)  raw per-half-chunk hist (accum -> redcent)
//  32768 : int counts[16]      (64)
//  32832 : int offsets[16]     (64)
//  32896 : float csq[16]       (64)
//  32960 : float pos_stat[16]  (64)
//  33024 : float neg_stat[256] (1024)
//  34048 : ushort cfb[4096]    (8192)   centers in bf16 MFMA A-fragment order
//  65536 : int bhist2[512*16]  (32768)  scanned bases (redcent -> dist)
// 131072 : float Dmat[16*65536] (4 MB) -- also partials[512][4096] (8 MB) pre-dist
// 16842752 : int slots[65536]  (256 KB) packed (lab<<16 | rank-within-half-chunk)

#define ACC_CASE(C) case C: acc[C][0] += xv[u].x; acc[C][1] += xv[u].y; \
                            acc[C][2] += xv[u].z; acc[C][3] += xv[u].w; break;

// 512 blocks x 128 rows (one half-chunk). Waves 0/1 also ballot-rank the 128
// labels -> slots + bhist. Two-phase 32KB LDS combine. 8-row staging for MLP
// (4-row staging left only ~4KB/wave in flight vs ~9KB needed for ~900cyc HBM
// latency at 10B/cyc/CU). No min-waves bound (R17 spill lesson).
__global__ void __launch_bounds__(256) k_accum(const float* __restrict__ x,
                                               const int* __restrict__ y,
                                               float* __restrict__ partials,
                                               int* __restrict__ bhist,
                                               int* __restrict__ slots) {
  __shared__ int labs[128];
  __shared__ int wcnt2[2][NC];
  __shared__ float red[2 * NC * DIM];  // 32 KB
  int t = threadIdx.x;
  int n0 = blockIdx.x * 128;
  if (t < 128) labs[t] = y[(n0 + t) * 3 + 2];
  __syncthreads();

  // merged histrank: waves 0,1 rank their 64 labels
  if (t < 128) {
    int lab = labs[t];
    int lane = t & 63, w2 = t >> 6;
    unsigned long long mymask = 0;
#pragma unroll
    for (int c = 0; c < NC; ++c) {
      unsigned long long mk = __ballot(lab == c);
      if (lane == 0) wcnt2[w2][c] = __popcll(mk);
      if (lab == c) mymask = mk;
    }
    int rank = __popcll(mymask & ((1ull << lane) - 1ull));
    slots[n0 + t] = (lab << 16) | rank;  // w2==1 corrected after sync
  }
  __syncthreads();
  if (t >= 64 && t < 128) {
    int lab = labs[t];
    slots[n0 + t] += wcnt2[0][lab];
  }
  if (t < NC) bhist[blockIdx.x * NC + t] = wcnt2[0][t] + wcnt2[1][t];

  int w = t >> 6, m = t & 63;
  float acc[NC][4];
#pragma unroll
  for (int c = 0; c < NC; ++c)
#pragma unroll
    for (int j = 0; j < 4; ++j) acc[c][j] = 0.f;

#pragma unroll 1
  for (int r0 = 0; r0 < 32; r0 += 8) {
    float4 xv[8];
#pragma unroll
    for (int u = 0; u < 8; ++u)
      xv[u] = *(const float4*)(x + (size_t)(n0 + 32 * w + r0 + u) * DIM + 4 * m);
#pragma unroll
    for (int u = 0; u < 8; ++u) {
      int lab = __builtin_amdgcn_readfirstlane(labs[32 * w + r0 + u]);
      switch (lab) {
        ACC_CASE(0) ACC_CASE(1) ACC_CASE(2) ACC_CASE(3)
        ACC_CASE(4) ACC_CASE(5) ACC_CASE(6) ACC_CASE(7)
        ACC_CASE(8) ACC_CASE(9) ACC_CASE(10) ACC_CASE(11)
        ACC_CASE(12) ACC_CASE(13) ACC_CASE(14) ACC_CASE(15)
      }
    }
  }

  int half = w & 1;
  if (w < 2) {
#pragma unroll
    for (int c = 0; c < NC; ++c)
#pragma unroll
      for (int j = 0; j < 4; ++j)
        red[half * (NC * DIM) + c * DIM + 4 * m + j] = acc[c][j];
  }
  __syncthreads();
  if (w >= 2) {
#pragma unroll
    for (int c = 0; c < NC; ++c)
#pragma unroll
      for (int j = 0; j < 4; ++j)
        red[half * (NC * DIM) + c * DIM + 4 * m + j] += acc[c][j];
  }
  __syncthreads();
  for (int u = t; u < NC * DIM; u += 256)
    partials[(size_t)blockIdx.x * (NC * DIM) + u] = red[u] + red[NC * DIM + u];
}

// 17 blocks x 1024 thr. Blocks 0-15: class c reduce (4-slice) + count + cfb/csq.
// Block 16: scan bhist -> bhist2 + counts/offsets.
__global__ void __launch_bounds__(1024) k_redcent(const float* __restrict__ partials,
                                                  const int* __restrict__ bhist,
                                                  int* __restrict__ bhist2,
                                                  int* __restrict__ counts,
                                                  int* __restrict__ offsets,
                                                  float* __restrict__ csq,
                                                  unsigned short* __restrict__ cfb) {
  __shared__ int lh[512 * NC];
  __shared__ float sl[4 * 256];
  __shared__ int segbase[16][NC];
  __shared__ int totl[NC], offl[NC];
  __shared__ int wredi[16];
  __shared__ int cnt_sh;
  __shared__ float wsum[4];
  int t = threadIdx.x;

  if (blockIdx.x < 16) {
    int c = blockIdx.x;
    int d = t & 255, s = t >> 8;
    float a = 0.f;
#pragma unroll 8
    for (int b = s * 128; b < s * 128 + 128; ++b)
      a += partials[(size_t)b * (NC * DIM) + c * DIM + d];
    sl[s * 256 + d] = a;

    int lane = t & 63, wv = t >> 6;
    int v = (t < 512) ? bhist[t * NC + c] : 0;
#pragma unroll
    for (int m = 1; m < 64; m <<= 1) v += __shfl_xor(v, m);
    if (lane == 0) wredi[wv] = v;
    __syncthreads();
    if (t == 0) {
      int cn = 0;
#pragma unroll
      for (int w2 = 0; w2 < 16; ++w2) cn += wredi[w2];
      cnt_sh = cn;
    }
    __syncthreads();
    if (s == 0) {
      float v4 = sl[d] + sl[256 + d] + sl[512 + d] + sl[768 + d];
      float vc = v4 / (float)cnt_sh + EPSV;
      unsigned int bits = __float_as_uint(vc);
      unsigned short h = (unsigned short)((bits + 0x7FFFu + ((bits >> 16) & 1u)) >> 16);
      int kc = d >> 5, lg = (d >> 3) & 3, j = d & 7;
      int l = lg * 16 + c;
      cfb[kc * 512 + l * 8 + j] = h;
      float q = vc * vc;
#pragma unroll
      for (int m = 1; m < 64; m <<= 1) q += __shfl_xor(q, m);
      if ((d & 63) == 0) wsum[d >> 6] = q;
    }
    __syncthreads();
    if (t == 0) csq[c] = wsum[0] + wsum[1] + wsum[2] + wsum[3];
  } else {
    for (int u = t; u < 512 * NC; u += 1024) lh[u] = bhist[u];
    __syncthreads();
    if (t < 256) {
      int c = t & 15, g = t >> 4;
      int part = 0;
#pragma unroll
      for (int b = 0; b < 32; ++b) part += lh[(g * 32 + b) * NC + c];
      segbase[g][c] = part;
    }
    __syncthreads();
    if (t < NC) {
      int tot = 0;
#pragma unroll
      for (int g2 = 0; g2 < 16; ++g2) tot += segbase[g2][t];
      totl[t] = tot;
      counts[t] = tot;
    }
    __syncthreads();
    if (t == 0) {
      int run = 0;
      for (int c2 = 0; c2 < NC; ++c2) { offl[c2] = run; offsets[c2] = run; run += totl[c2]; }
    }
    __syncthreads();
    if (t < NC) {
      int run = offl[t];
#pragma unroll
      for (int g2 = 0; g2 < 16; ++g2) { int tmp = segbase[g2][t]; segbase[g2][t] = run; run += tmp; }
    }
    __syncthreads();
    if (t < 256) {
      int c = t & 15, g = t >> 4;
      int run = segbase[g][c];
#pragma unroll
      for (int b = 0; b < 32; ++b) {
        int idx = (g * 32 + b) * NC + c;
        int tmp = lh[idx]; lh[idx] = run; run += tmp;
      }
    }
    __syncthreads();
    for (int u = t; u < 512 * NC; u += 1024) bhist2[u] = lh[u];
  }
}

__device__ __forceinline__ unsigned int cvt_pk_bf16(float lo, float hi) {
  unsigned int r;
  asm("v_cvt_pk_bf16_f32 %0, %1, %2" : "=v"(r) : "v"(lo), "v"(hi));
  return r;
}

// MFMA k_dist: D = centers(bf16) . x(bf16), xsq fp32.
__global__ void __launch_bounds__(256) k_dist(const float* __restrict__ x,
                                              const unsigned short* __restrict__ cfb,
                                              const float* __restrict__ csq,
                                              const int* __restrict__ slots,
                                              const int* __restrict__ bbase,
                                              float* __restrict__ Dmat) {
  __shared__ float csql[NC];
  __shared__ int baseL[NC];
  __shared__ int slotL[64];
  int t = threadIdx.x;
  if (t < NC) {
    csql[t] = csq[t];
    baseL[t] = bbase[(blockIdx.x >> 1) * NC + t];
  }
  __syncthreads();
  int pbase = blockIdx.x * 64;
  if (t < 64) {
    int sp = slots[pbase + t];
    slotL[t] = baseL[sp >> 16] + (sp & 0xFFFF);
  }
  __syncthreads();

  int wave = t >> 6, l = t & 63;
  int lg = l >> 4;
  int pl = wave * 16 + (l & 15);
  int p = pbase + pl;

  const float4* xrow = (const float4*)(x + (size_t)p * DIM);
  float4 xa[8][2];
#pragma unroll
  for (int kc = 0; kc < 8; ++kc) {
    xa[kc][0] = xrow[kc * 8 + lg * 2 + 0];
    xa[kc][1] = xrow[kc * 8 + lg * 2 + 1];
  }

  float xsq = 0.f;
#pragma unroll
  for (int kc = 0; kc < 8; ++kc) {
    float4 a0 = xa[kc][0], a1 = xa[kc][1];
    xsq += a0.x * a0.x + a0.y * a0.y + a0.z * a0.z + a0.w * a0.w +
           a1.x * a1.x + a1.y * a1.y + a1.z * a1.z + a1.w * a1.w;
  }
  xsq += __shfl_xor(xsq, 16);
  xsq += __shfl_xor(xsq, 32);

  const uint4* cfp = (const uint4*)cfb;
  f32x4 acc = {0.f, 0.f, 0.f, 0.f};
#pragma unroll
  for (int kc = 0; kc < 8; ++kc) {
    union { unsigned int u[4]; short8v s; } xb, cf;
    float4 a0 = xa[kc][0], a1 = xa[kc][1];
    xb.u[0] = cvt_pk_bf16(a0.x, a0.y);
    xb.u[1] = cvt_pk_bf16(a0.z, a0.w);
    xb.u[2] = cvt_pk_bf16(a1.x, a1.y);
    xb.u[3] = cvt_pk_bf16(a1.z, a1.w);
    uint4 cw = cfp[kc * 64 + l];
    cf.u[0] = cw.x; cf.u[1] = cw.y; cf.u[2] = cw.z; cf.u[3] = cw.w;
    acc = __builtin_amdgcn_mfma_f32_16x16x32_bf16(cf.s, xb.s, acc, 0, 0, 0);
  }

  int slot = slotL[pl];
#pragma unroll
  for (int j = 0; j < 4; ++j) {
    int m = lg * 4 + j;
    float d2 = csql[m] - 2.f * acc[j] + xsq;
    Dmat[(size_t)m * NPTS + slot] = sqrtf(fmaxf(d2, 0.f));
  }
}

// Radix-select; bin location via wave-0 hierarchical find (no block scans).
__global__ void __launch_bounds__(512) k_select(const float* __restrict__ Dmat,
                                                const int* __restrict__ gcounts,
                                                const int* __restrict__ offsets,
                                                float* __restrict__ pos_stat,
                                                float* __restrict__ neg_stat) {
  __shared__ unsigned int keys[VMAX];
  __shared__ int hist[2048];
  __shared__ int bsel[2];
  __shared__ float wsumf[8];
  __shared__ int wsumi[8];
  int tid = threadIdx.x;
  int lane = tid & 63, wv = tid >> 6;
  int b = blockIdx.x;
  int ci = b >> 4, cl = b & 15;
  bool largest = (ci == cl);
  int cnt = gcounts[cl];
  if (cnt > VMAX) cnt = VMAX;
  int off = offsets[cl];
  const float* src = Dmat + (size_t)ci * NPTS + off;
  unsigned int inv = largest ? 0xFFFFFFFFu : 0u;
  for (int t = tid; t < cnt; t += 512) keys[t] = __float_as_uint(src[t]) ^ inv;
  __syncthreads();

  int target = KSEL;
  unsigned int pfx = 0;

  for (int u = tid; u < 2048; u += 512) hist[u] = 0;
  __syncthreads();
  for (int t = tid; t < cnt; t += 512) atomicAdd(&hist[keys[t] >> 21], 1);
  __syncthreads();
  if (tid < 64) {
    int own = 0;
#pragma unroll
    for (int j = 0; j < 32; ++j) own += hist[lane * 32 + j];
    int incl = own;
    for (int o = 1; o < 64; o <<= 1) { int n = __shfl_up(incl, o); if (lane >= o) incl += n; }
    int excl = incl - own;
    unsigned long long mk = __ballot(excl < target && target <= incl);
    int sel = __ffsll((unsigned long long)mk) - 1;
    if (lane == sel) {
      int run = excl;
      for (int j = 0; j < 32; ++j) {
        int h = hist[lane * 32 + j];
        if (run < target && target <= run + h) { bsel[0] = lane * 32 + j; bsel[1] = target - run; }
        run += h;
      }
    }
  }
  __syncthreads();
  pfx = ((unsigned int)bsel[0]) << 21; target = bsel[1];
  __syncthreads();

  for (int u = tid; u < 2048; u += 512) hist[u] = 0;
  __syncthreads();
  for (int t = tid; t < cnt; t += 512) {
    unsigned int k = keys[t];
    if ((k >> 21) == (pfx >> 21)) atomicAdd(&hist[(k >> 10) & 0x7FF], 1);
  }
  __syncthreads();
  if (tid < 64) {
    int own = 0;
#pragma unroll
    for (int j = 0; j < 32; ++j) own += hist[lane * 32 + j];
    int incl = own;
    for (int o = 1; o < 64; o <<= 1) { int n = __shfl_up(incl, o); if (lane >= o) incl += n; }
    int excl = incl - own;
    unsigned long long mk = __ballot(excl < target && target <= incl);
    int sel = __ffsll((unsigned long long)mk) - 1;
    if (lane == sel) {
      int run = excl;
      for (int j = 0; j < 32; ++j) {
        int h = hist[lane * 32 + j];
        if (run < target && target <= run + h) { bsel[0] = lane * 32 + j; bsel[1] = target - run; }
        run += h;
      }
    }
  }
  __syncthreads();
  pfx |= ((unsigned int)bsel[0]) << 10; target = bsel[1];
  __syncthreads();

  for (int u = tid; u < 1024; u += 512) hist[u] = 0;
  __syncthreads();
  for (int t = tid; t < cnt; t += 512) {
    unsigned int k = keys[t];
    if ((k >> 10) == (pfx >> 10)) atomicAdd(&hist[k & 0x3FF], 1);
  }
  __syncthreads();
  if (tid < 64) {
    int own = 0;
#pragma unroll
    for (int j = 0; j < 16; ++j) own += hist[lane * 16 + j];
    int incl = own;
    for (int o = 1; o < 64; o <<= 1) { int n = __shfl_up(incl, o); if (lane >= o) incl += n; }
    int excl = incl - own;
    unsigned long long mk = __ballot(excl < target && target <= incl);
    int sel = __ffsll((unsigned long long)mk) - 1;
    if (lane == sel) {
      int run = excl;
      for (int j = 0; j < 16; ++j) {
        int h = hist[lane * 16 + j];
        if (run < target && target <= run + h) { bsel[0] = lane * 16 + j; }
        run += h;
      }
    }
  }
  __syncthreads();
  unsigned int T = pfx | (unsigned int)bsel[0];
  float fT = __uint_as_float(T ^ inv);

  int nl = 0; float sl = 0.f;
  for (int t = tid; t < cnt; t += 512) {
    unsigned int k = keys[t];
    if (k < T) { nl++; sl += __uint_as_float(k ^ inv); }
  }
#pragma unroll
  for (int m = 1; m < 64; m <<= 1) { nl += __shfl_xor(nl, m); sl += __shfl_xor(sl, m); }
  if (lane == 0) { wsumi[wv] = nl; wsumf[wv] = sl; }
  __syncthreads();
  int n_less = 0; float s_less = 0.f;
#pragma unroll
  for (int w2 = 0; w2 < 8; ++w2) { n_less += wsumi[w2]; s_less += wsumf[w2]; }
  float mean = (s_less + (float)(KSEL - n_less) * fT) / (float)KSEL;
  __syncthreads();

  float sv = 0.f;
  for (int t = tid; t < cnt; t += 512) {
    unsigned int k = keys[t];
    if (k < T) { float d = __uint_as_float(k ^ inv) - mean; sv += d * d; }
  }
#pragma unroll
  for (int m = 1; m < 64; m <<= 1) sv += __shfl_xor(sv, m);
  if (lane == 0) wsumf[wv] = sv;
  __syncthreads();
  if (tid == 0) {
    float vs = 0.f;
#pragma unroll
    for (int w2 = 0; w2 < 8; ++w2) vs += wsumf[w2];
    float dT = fT - mean;
    float var = (vs + (float)(KSEL - n_less) * dT * dT) / (float)(KSEL - 1);
    if (largest) pos_stat[ci] = mean + 1.96f * sqrtf(var);
    else neg_stat[ci * 16 + cl] = mean - 1.96f * sqrtf(var);
  }
}

__global__ void __launch_bounds__(256) k_loss(const float* __restrict__ pos_stat,
                                              const float* __restrict__ neg_stat,
                                              float* __restrict__ out) {
  __shared__ float red[256];
  int t = threadIdx.x;
  int i = t >> 4, c = t & 15;
  float v = 0.f;
  if (i != c) v = fmaxf(1.0f + pos_stat[i] - neg_stat[t], 0.f);
  red[t] = v; __syncthreads();
  for (int st = 128; st > 0; st >>= 1) { if (t < st) red[t] += red[t + st]; __syncthreads(); }
  if (t == 0) out[0] = red[0];
}

extern "C" void kernel_launch(void* const* d_in, const int* in_sizes, int n_in,
                              void* d_out, int out_size, void* d_ws, size_t ws_size,
                              hipStream_t stream) {
  const float* x = (const float*)d_in[0];
  const int* y = (const int*)d_in[1];
  float* out = (float*)d_out;
  char* ws = (char*)d_ws;

  int* bhist = (int*)(ws + 0);
  int* counts = (int*)(ws + 32768);
  int* offsets = (int*)(ws + 32832);
  float* csq = (float*)(ws + 32896);
  float* pos_stat = (float*)(ws + 32960);
  float* neg_stat = (float*)(ws + 33024);
  unsigned short* cfb = (unsigned short*)(ws + 34048);
  int* bhist2 = (int*)(ws + 65536);
  float* Dmat = (float*)(ws + 131072);
  float* partials = (float*)(ws + 131072);  // [512][4096] = 8 MB, consumed pre-dist
  int* slots = (int*)(ws + 16842752);

  k_accum<<<512, 256, 0, stream>>>(x, y, partials, bhist, slots);
  k_redcent<<<17, 1024, 0, stream>>>(partials, bhist, bhist2, counts, offsets, csq, cfb);
  k_dist<<<1024, 256, 0, stream>>>(x, cfb, csq, slots, bhist2, Dmat);
  k_select<<<256, 512, 0, stream>>>(Dmat, counts, offsets, pos_stat, neg_stat);
  k_loss<<<1, 256, 0, stream>>>(pos_stat, neg_stat, out);
}